// Round 6
// baseline (2830.386 us; speedup 1.0000x reference)
//
#include <hip/hip_runtime.h>
#include <cstdint>
#include <cstddef>

typedef unsigned short u16;
typedef unsigned long long u64;
typedef __attribute__((ext_vector_type(4))) float f32x4;
typedef __attribute__((ext_vector_type(8))) short s16x8;

#define T_STEPS 512
#define OUT_MAIN 16777216   // 512*64*512
#define HQSLOT 32768        // u64 per parity slot: 64 batches * 512 units

// ---------- bf16 split helpers (bit-level RNE) ----------
static __device__ __forceinline__ u16 f2bf(float f) {
  unsigned u = __builtin_bit_cast(unsigned, f);
  unsigned r = u + 0x7FFFu + ((u >> 16) & 1u);
  return (u16)(r >> 16);
}
static __device__ __forceinline__ float bf2f(u16 h) {
  unsigned u = ((unsigned)h) << 16;
  return __builtin_bit_cast(float, u);
}

// ---------- init: W transpose+split, h0 -> packed u64 (seq0), c0, no flags ----------
__global__ void init_k(const float* __restrict__ W, const float* __restrict__ h0,
                       const float* __restrict__ c0,
                       u16* __restrict__ wthi, u16* __restrict__ wtlo,
                       u64* __restrict__ hq, float* __restrict__ cws) {
  const int NW = 1024 * 2048;  // full W (Wx rows 0..511, Wh rows 512..1023)
  const int NH = 64 * 512;
  const int total = NW + 2 * NH;
  for (int idx = blockIdx.x * blockDim.x + threadIdx.x; idx < total;
       idx += gridDim.x * blockDim.x) {
    if (idx < NW) {
      int k = idx >> 11;          // row of W (0..1023)
      int c = idx & 2047;         // gate column
      float wv = W[idx];
      u16 hi = f2bf(wv);
      wthi[(size_t)c * 1024 + k] = hi;
      wtlo[(size_t)c * 1024 + k] = f2bf(wv - bf2f(hi));
    } else if (idx < NW + NH) {
      int r = idx - NW;           // batch*512 + unit
      float v = h0[r];
      u16 hi = f2bf(v);
      u16 lo = f2bf(v - bf2f(hi));
      // slot 0, seq 0: [seq32 | hi16 | lo16]
      hq[r] = ((u64)(unsigned)hi << 16) | (u64)(unsigned)lo;
    } else {
      int r = idx - NW - NH;
      cws[r] = c0[r];
    }
  }
}

// ---------- x chunk -> bf16 hi/lo ----------
__global__ void convx_k(const float* __restrict__ x, u16* __restrict__ hi,
                        u16* __restrict__ lo, int n4) {
  for (int i = blockIdx.x * blockDim.x + threadIdx.x; i < n4;
       i += gridDim.x * blockDim.x) {
    float4 v = ((const float4*)x)[i];
    ushort4 h, l2;
    h.x = f2bf(v.x); l2.x = f2bf(v.x - bf2f(h.x));
    h.y = f2bf(v.y); l2.y = f2bf(v.y - bf2f(h.y));
    h.z = f2bf(v.z); l2.z = f2bf(v.z - bf2f(h.z));
    h.w = f2bf(v.w); l2.w = f2bf(v.w - bf2f(h.w));
    ((ushort4*)hi)[i] = h;
    ((ushort4*)lo)[i] = l2;
  }
}

// ---------- G = x@Wx + b : 128x128 tile, 4 waves, 3-term bf16-split MFMA ----------
__global__ void __launch_bounds__(256, 2)
gemm_k(const u16* __restrict__ xhi, const u16* __restrict__ xlo,
       const u16* __restrict__ wthi, const u16* __restrict__ wtlo,
       const float* __restrict__ bias, float* __restrict__ Gout) {
  __shared__ u16 Ah[4096], Al[4096], Bh[4096], Bl[4096];   // [128][32] each
  const int tid = threadIdx.x;
  const int nb = blockIdx.x & 15;
  const int mb = blockIdx.x >> 4;
  const int w = tid >> 6, l = tid & 63;
  const int wm = w >> 1, wn = w & 1;
  const int lr = l & 15, lq = l >> 4;

  const int pos0 = tid, pos1 = tid + 256;
  const int row0 = pos0 >> 2, row1 = pos1 >> 2;
  const int cc = (tid & 3) * 8;
  const size_t aOff0 = (size_t)(mb * 128 + row0) * 512 + cc;
  const size_t aOff1 = (size_t)(mb * 128 + row1) * 512 + cc;
  const size_t bOff0 = (size_t)(nb * 128 + row0) * 1024 + cc;
  const size_t bOff1 = (size_t)(nb * 128 + row1) * 1024 + cc;

  float bv[4];
  #pragma unroll
  for (int n = 0; n < 4; ++n) bv[n] = bias[nb * 128 + wn * 64 + n * 16 + lr];

  f32x4 acc[4][4] = {};
  s16x8 rA0, rA1, rAl0, rAl1, rB0, rB1, rBl0, rBl1;
  rA0  = *(const s16x8*)(xhi  + aOff0);
  rA1  = *(const s16x8*)(xhi  + aOff1);
  rAl0 = *(const s16x8*)(xlo  + aOff0);
  rAl1 = *(const s16x8*)(xlo  + aOff1);
  rB0  = *(const s16x8*)(wthi + bOff0);
  rB1  = *(const s16x8*)(wthi + bOff1);
  rBl0 = *(const s16x8*)(wtlo + bOff0);
  rBl1 = *(const s16x8*)(wtlo + bOff1);

  for (int kt = 0; kt < 16; ++kt) {
    *(s16x8*)&Ah[pos0 * 8] = rA0;  *(s16x8*)&Ah[pos1 * 8] = rA1;
    *(s16x8*)&Al[pos0 * 8] = rAl0; *(s16x8*)&Al[pos1 * 8] = rAl1;
    *(s16x8*)&Bh[pos0 * 8] = rB0;  *(s16x8*)&Bh[pos1 * 8] = rB1;
    *(s16x8*)&Bl[pos0 * 8] = rBl0; *(s16x8*)&Bl[pos1 * 8] = rBl1;
    __syncthreads();
    if (kt < 15) {
      const int k0 = (kt + 1) * 32;
      rA0  = *(const s16x8*)(xhi  + aOff0 + k0);
      rA1  = *(const s16x8*)(xhi  + aOff1 + k0);
      rAl0 = *(const s16x8*)(xlo  + aOff0 + k0);
      rAl1 = *(const s16x8*)(xlo  + aOff1 + k0);
      rB0  = *(const s16x8*)(wthi + bOff0 + k0);
      rB1  = *(const s16x8*)(wthi + bOff1 + k0);
      rBl0 = *(const s16x8*)(wtlo + bOff0 + k0);
      rBl1 = *(const s16x8*)(wtlo + bOff1 + k0);
    }
    s16x8 fAh[4], fAl[4], fBh[4], fBl[4];
    #pragma unroll
    for (int mm = 0; mm < 4; ++mm) {
      const int rrow = wm * 64 + mm * 16 + lr;
      fAh[mm] = *(const s16x8*)&Ah[rrow * 32 + lq * 8];
      fAl[mm] = *(const s16x8*)&Al[rrow * 32 + lq * 8];
    }
    #pragma unroll
    for (int nn = 0; nn < 4; ++nn) {
      const int crow = wn * 64 + nn * 16 + lr;
      fBh[nn] = *(const s16x8*)&Bh[crow * 32 + lq * 8];
      fBl[nn] = *(const s16x8*)&Bl[crow * 32 + lq * 8];
    }
    #pragma unroll
    for (int mm = 0; mm < 4; ++mm)
      #pragma unroll
      for (int nn = 0; nn < 4; ++nn) {
        acc[mm][nn] = __builtin_amdgcn_mfma_f32_16x16x32_bf16(fAh[mm], fBh[nn], acc[mm][nn], 0, 0, 0);
        acc[mm][nn] = __builtin_amdgcn_mfma_f32_16x16x32_bf16(fAh[mm], fBl[nn], acc[mm][nn], 0, 0, 0);
        acc[mm][nn] = __builtin_amdgcn_mfma_f32_16x16x32_bf16(fAl[mm], fBh[nn], acc[mm][nn], 0, 0, 0);
      }
    __syncthreads();
  }
  #pragma unroll
  for (int mm = 0; mm < 4; ++mm)
    #pragma unroll
    for (int nn = 0; nn < 4; ++nn)
      #pragma unroll
      for (int i = 0; i < 4; ++i) {
        const int row = mb * 128 + wm * 64 + mm * 16 + lq * 4 + i;
        const int col = nb * 128 + wn * 64 + nn * 16 + lr;
        Gout[(size_t)row * 2048 + col] = acc[mm][nn][i] + bv[nn];
      }
}

// ---------- recurrence v4: seq-in-data u64 publish (single-hop sync, no flags,
//            no producer ack), per-wave independent poll, 1 barrier/step,
//            epilogue spread over all 4 waves ----------
__global__ void __launch_bounds__(256, 1)
rec_k(const u16* __restrict__ wthi, const u16* __restrict__ wtlo,
      const float* __restrict__ Gbuf, u64* __restrict__ hq,
      float* __restrict__ cws, float* __restrict__ out, int t0, int Tc) {
  const int g = blockIdx.x & 7;        // group (XCD heuristic; perf-only)
  const int m = blockIdx.x >> 3;       // member 0..31: owns hidden units [16m,16m+16)
  const int tid = threadIdx.x;
  const int w = tid >> 6;              // wave = K-slice [w*128, w*128+128)
  const int l = tid & 63;
  const int lr = l & 15, lq = l >> 4;

  __shared__ float part[2][4][8][64];  // [parity][wave][batch][gate*16+unit]

  // --- B fragments: wave w's K-slice of Wh, all 4 gates, bf16 hi/lo, in regs ---
  s16x8 bhi[4][4], blo[4][4];
  #pragma unroll
  for (int nt = 0; nt < 4; ++nt) {
    const size_t cb = (size_t)(nt * 512 + m * 16 + lr) * 1024 + 512 + w * 128 + lq * 8;
    #pragma unroll
    for (int kt = 0; kt < 4; ++kt) {
      bhi[kt][nt] = *(const s16x8*)(wthi + cb + kt * 32);
      blo[kt][nt] = *(const s16x8*)(wtlo + cb + kt * 32);
    }
  }

  // epilogue mapping: lanes l<32 of wave w own (batch eb, unit eu)
  const int eb = 2 * w + (l >> 4);     // valid for l<32
  const int eu = l & 15;
  float cr = 0.f;
  if (l < 32) cr = cws[(size_t)(g * 8 + eb) * 512 + m * 16 + eu];

  // poll source base for this lane's A-fragment row (global batch g*8+lr)
  const int rowBase = (g * 8 + lr) * 512 + w * 128 + lq * 8;

  for (int tl = 0; tl < Tc; ++tl) {
    const int t = t0 + tl;
    // early x-gate loads (plain, cacheable; hide HBM latency under the poll)
    float gvf = 0.f, gvi = 0.f, gvc = 0.f, gvo = 0.f;
    if (l < 32) {
      const float* gp = Gbuf + ((size_t)tl * 64 + g * 8 + eb) * 2048 + m * 16 + eu;
      gvf = gp[0]; gvi = gp[512]; gvc = gp[1024]; gvo = gp[1536];
    }
    // ---- single-hop poll: load own operand data, check embedded seq ----
    const u64* hp = hq + (size_t)(t & 1) * HQSLOT + rowBase;
    u64 q[4][8];
    int ok; unsigned spin = 0;
    do {
      unsigned bad = 0;
      if (lr < 8) {
        #pragma unroll
        for (int kt = 0; kt < 4; ++kt)
          #pragma unroll
          for (int j = 0; j < 8; ++j) {
            q[kt][j] = __hip_atomic_load(hp + kt * 32 + j, __ATOMIC_RELAXED,
                                         __HIP_MEMORY_SCOPE_AGENT);
            bad |= (unsigned)(q[kt][j] >> 32) ^ (unsigned)t;
          }
      }
      ok = __all(bad == 0);
      if (!ok) __builtin_amdgcn_s_sleep(1);
    } while (!ok && ++spin < (1u << 26));   // bounded: fail visibly, never wedge

    // unpack u64 -> bf16 hi/lo A fragments (pad rows 8..15 = zero regs)
    s16x8 ah[4], al[4];
    if (lr < 8) {
      #pragma unroll
      for (int kt = 0; kt < 4; ++kt)
        #pragma unroll
        for (int j = 0; j < 8; ++j) {
          unsigned d = (unsigned)q[kt][j];
          ah[kt][j] = (short)(d >> 16);
          al[kt][j] = (short)(d & 0xFFFFu);
        }
    } else {
      #pragma unroll
      for (int kt = 0; kt < 4; ++kt) {
        ah[kt] = (s16x8)(short)0; al[kt] = (s16x8)(short)0;
      }
    }

    f32x4 acc[4] = {};
    #pragma unroll
    for (int kt = 0; kt < 4; ++kt)
      #pragma unroll
      for (int nt = 0; nt < 4; ++nt) {
        acc[nt] = __builtin_amdgcn_mfma_f32_16x16x32_bf16(ah[kt], bhi[kt][nt], acc[nt], 0, 0, 0);
        acc[nt] = __builtin_amdgcn_mfma_f32_16x16x32_bf16(ah[kt], blo[kt][nt], acc[nt], 0, 0, 0);
        acc[nt] = __builtin_amdgcn_mfma_f32_16x16x32_bf16(al[kt], bhi[kt][nt], acc[nt], 0, 0, 0);
      }
    // per-wave K-partial -> parity-buffered LDS (C rows 0..7 live in lanes 0..31)
    const int p = tl & 1;
    if (l < 32) {
      #pragma unroll
      for (int nt = 0; nt < 4; ++nt)
        #pragma unroll
        for (int i = 0; i < 4; ++i)
          part[p][w][lq * 4 + i][nt * 16 + lr] = acc[nt][i];
    }
    __syncthreads();   // the ONLY barrier per step

    if (l < 32) {
      float ga[4];
      #pragma unroll
      for (int gi = 0; gi < 4; ++gi) {
        float s0 = part[p][0][eb][gi * 16 + eu];
        float s1 = part[p][1][eb][gi * 16 + eu];
        float s2 = part[p][2][eb][gi * 16 + eu];
        float s3 = part[p][3][eb][gi * 16 + eu];
        ga[gi] = (s0 + s1) + (s2 + s3);
      }
      float fg = ga[0] + gvf, ig = ga[1] + gvi;
      float cg = ga[2] + gvc, og = ga[3] + gvo;
      float fs = 1.f / (1.f + __expf(-fg));
      float is = 1.f / (1.f + __expf(-ig));
      float os = 1.f / (1.f + __expf(-og));
      float cgc = fminf(fmaxf(cg, -15.f), 15.f);
      float e2c = __expf(2.f * cgc);
      float cd = (e2c - 1.f) / (e2c + 1.f);
      cr = fs * cr + is * cd;
      float crc = fminf(fmaxf(cr, -15.f), 15.f);
      float e2h = __expf(2.f * crc);
      float th = (e2h - 1.f) / (e2h + 1.f);
      float hn = os * th;
      // publish: ONE u64 atomic store carries data + seq atomically
      u16 hh = f2bf(hn);
      u16 hl = f2bf(hn - bf2f(hh));
      u64 qv = ((u64)(unsigned)(t + 1) << 32) | ((u64)(unsigned)hh << 16) | (u64)(unsigned)hl;
      __hip_atomic_store(hq + (size_t)((t + 1) & 1) * HQSLOT +
                             (size_t)(g * 8 + eb) * 512 + m * 16 + eu,
                         qv, __ATOMIC_RELAXED, __HIP_MEMORY_SCOPE_AGENT);
      // non-critical stores after the publish
      out[((size_t)t * 64 + g * 8 + eb) * 512 + m * 16 + eu] = hn;
      if (t == T_STEPS - 1) {
        out[(size_t)OUT_MAIN + (size_t)(g * 8 + eb) * 512 + m * 16 + eu] = hn;
        out[(size_t)OUT_MAIN + 32768 + (size_t)(g * 8 + eb) * 512 + m * 16 + eu] = cr;
      }
      if (tl == Tc - 1)
        cws[(size_t)(g * 8 + eb) * 512 + m * 16 + eu] = cr;
    }
  }
}

// ---------- host ----------
extern "C" void kernel_launch(void* const* d_in, const int* in_sizes, int n_in,
                              void* d_out, int out_size, void* d_ws, size_t ws_size,
                              hipStream_t stream) {
  const float* x  = (const float*)d_in[0];
  const float* h0 = (const float*)d_in[1];
  const float* c0 = (const float*)d_in[2];
  const float* W  = (const float*)d_in[3];
  const float* bs = (const float*)d_in[4];
  float* out = (float*)d_out;

  auto need = [](int tc) -> size_t {
    size_t s = 0;
    s += (size_t)tc * 524288;     // G fp32
    s += (size_t)tc * 131072;     // x hi+lo bf16
    s += 2 * (size_t)4194304;     // W^T hi+lo (full 1024 rows)
    s += 524288;                  // hq (2 parity slots of u64)
    s += 131072;                  // c state
    s += 8192;                    // alignment slack
    return s;
  };
  int Tc = 512;
  while (Tc > 2 && need(Tc) > ws_size) Tc >>= 1;

  char* p = (char*)d_ws;
  auto alloc = [&](size_t bytes) -> char* {
    char* r = p;
    p += (bytes + 255) & ~(size_t)255;
    return r;
  };
  float* Gbuf = (float*)alloc((size_t)Tc * 524288);
  u16* xhi  = (u16*)alloc((size_t)Tc * 65536);
  u16* xlo  = (u16*)alloc((size_t)Tc * 65536);
  u16* wthi = (u16*)alloc(4194304);
  u16* wtlo = (u16*)alloc(4194304);
  u64* hq   = (u64*)alloc(524288);
  float* cws = (float*)alloc(131072);

  hipLaunchKernelGGL(init_k, dim3(1024), dim3(256), 0, stream,
                     W, h0, c0, wthi, wtlo, hq, cws);
  const int nch = 512 / Tc;
  for (int ck = 0; ck < nch; ++ck) {
    const float* xck = x + (size_t)ck * Tc * 64 * 512;
    int n4 = Tc * 64 * 512 / 4;
    hipLaunchKernelGGL(convx_k, dim3(1024), dim3(256), 0, stream, xck, xhi, xlo, n4);
    hipLaunchKernelGGL(gemm_k, dim3(Tc / 2 * 16), dim3(256), 0, stream,
                       xhi, xlo, wthi, wtlo, bs, Gbuf);
    hipLaunchKernelGGL(rec_k, dim3(256), dim3(256), 0, stream,
                       wthi, wtlo, Gbuf, hq, cws, out, ck * Tc, Tc);
  }
}